// Round 2
// baseline (118.670 us; speedup 1.0000x reference)
//
#include <hip/hip_runtime.h>

// Holt-Winters triple exponential smoothing, 32768 windows x 511 steps.
// One thread per window; seasonal state S[24] kept in registers via full
// 24-step unroll (all indices compile-time constants). One-block-ahead
// register prefetch hides load latency (only ~2 waves/CU exist -> no TLP).

#define F_WINDOW 512
#define SEASONP  24
#define HORIZON  12

// One smoothing step. si MUST be a compile-time constant after unroll.
// u-form for bn: bn = (1-ab)*b - ab*L + ab*(xi-Sv)  (no dependence on Ln ->
// critical path per step is 2 dependent VALU ops for both L and b chains).
#define HW_STEP(xi, si) do {                       \
    const float Sv  = S[si];                       \
    const float d   = (xi) - Sv;                   \
    const float ad  = alpha * d;        /* a*d  */ \
    const float s_  = L + b;                       \
    const float Ln  = fmaf(oma, s_, ad);           \
    const float abd = beta * ad;        /* ab*d */ \
    const float tb  = fmaf(omab, b, abd);          \
    const float bn  = fmaf(ab, -L, tb);            \
    const float e   = (xi) - Ln;                   \
    const float gs  = omg * Sv;                    \
    S[si] = fmaf(gamma, e, gs);                    \
    L = Ln; b = bn;                                \
} while (0)

// 24 steps consuming 6 float4, seasonal indices (4+k)%24 (block starts i%24==4).
#define HW_BLOCK24(v0, v1, v2, v3, v4, v5) do {                                  \
    HW_STEP(v0.x,  4); HW_STEP(v0.y,  5); HW_STEP(v0.z,  6); HW_STEP(v0.w,  7); \
    HW_STEP(v1.x,  8); HW_STEP(v1.y,  9); HW_STEP(v1.z, 10); HW_STEP(v1.w, 11); \
    HW_STEP(v2.x, 12); HW_STEP(v2.y, 13); HW_STEP(v2.z, 14); HW_STEP(v2.w, 15); \
    HW_STEP(v3.x, 16); HW_STEP(v3.y, 17); HW_STEP(v3.z, 18); HW_STEP(v3.w, 19); \
    HW_STEP(v4.x, 20); HW_STEP(v4.y, 21); HW_STEP(v4.z, 22); HW_STEP(v4.w, 23); \
    HW_STEP(v5.x,  0); HW_STEP(v5.y,  1); HW_STEP(v5.z,  2); HW_STEP(v5.w,  3); \
} while (0)

__global__ __launch_bounds__(64) void holtwinter_kernel(
    const float* __restrict__ x,
    const float* __restrict__ y,
    const float* __restrict__ init_L,
    const float* __restrict__ init_b,
    const float* __restrict__ init_S,
    const float* __restrict__ p_alpha,
    const float* __restrict__ p_beta,
    const float* __restrict__ p_gamma,
    float* __restrict__ out)
{
    const int n = blockIdx.x * 64 + threadIdx.x;

    // Uniform scalars -> compiler scalarizes these loads.
    const float alpha = p_alpha[0];
    const float beta  = p_beta[0];
    const float gamma = p_gamma[0];
    const float oma   = 1.0f - alpha;
    const float ab    = alpha * beta;
    const float omab  = 1.0f - ab;
    const float omg   = 1.0f - gamma;

    const float* __restrict__ xr = x + (size_t)n * F_WINDOW;

    // Seasonal state in registers. Row is 96B-aligned (96 = 6*16) -> float4 ok.
    float S[SEASONP];
    {
        const float4* iS4 = (const float4*)(init_S + (size_t)n * SEASONP);
        float4 s0 = iS4[0], s1 = iS4[1], s2 = iS4[2];
        float4 s3 = iS4[3], s4 = iS4[4], s5 = iS4[5];
        S[0]=s0.x;  S[1]=s0.y;  S[2]=s0.z;  S[3]=s0.w;
        S[4]=s1.x;  S[5]=s1.y;  S[6]=s1.z;  S[7]=s1.w;
        S[8]=s2.x;  S[9]=s2.y;  S[10]=s2.z; S[11]=s2.w;
        S[12]=s3.x; S[13]=s3.y; S[14]=s3.z; S[15]=s3.w;
        S[16]=s4.x; S[17]=s4.y; S[18]=s4.z; S[19]=s4.w;
        S[20]=s5.x; S[21]=s5.y; S[22]=s5.z; S[23]=s5.w;
    }

    float L = init_L[n];
    float b = init_b[n];

    // Prologue: i = 1..3 (si = 1,2,3). Row base is 2KB-aligned -> float4.
    {
        const float4 v = *(const float4*)(xr);   // x[0..3]; x[0] unused
        HW_STEP(v.y, 1);
        HW_STEP(v.z, 2);
        HW_STEP(v.w, 3);
    }

    // Main: 21 blocks of 24 steps, i = 4..507, one-block-ahead prefetch.
    float4 c0, c1, c2, c3, c4, c5;
    {
        const float* __restrict__ xp = xr + 4;
        c0 = *(const float4*)(xp +  0);
        c1 = *(const float4*)(xp +  4);
        c2 = *(const float4*)(xp +  8);
        c3 = *(const float4*)(xp + 12);
        c4 = *(const float4*)(xp + 16);
        c5 = *(const float4*)(xp + 20);
    }
    #pragma unroll 2   // ping-pong: boundary copies rename away
    for (int blk = 0; blk < 20; ++blk) {
        const float* __restrict__ np = xr + 4 + (blk + 1) * 24;
        const float4 n0 = *(const float4*)(np +  0);
        const float4 n1 = *(const float4*)(np +  4);
        const float4 n2 = *(const float4*)(np +  8);
        const float4 n3 = *(const float4*)(np + 12);
        const float4 n4 = *(const float4*)(np + 16);
        const float4 n5 = *(const float4*)(np + 20);

        HW_BLOCK24(c0, c1, c2, c3, c4, c5);   // compute overlaps the loads

        c0 = n0; c1 = n1; c2 = n2; c3 = n3; c4 = n4; c5 = n5;
    }
    HW_BLOCK24(c0, c1, c2, c3, c4, c5);       // block 20 (i = 484..507)

    // Tail: i = 508..511, si = 4..7.
    {
        const float4 v = *(const float4*)(xr + 508);
        HW_STEP(v.x, 4); HW_STEP(v.y, 5); HW_STEP(v.z, 6); HW_STEP(v.w, 7);
    }

    // Forecast & loss term. s_idx = (511 + 12) % 24 = 19.
    const float f    = fmaf((float)HORIZON, b, L) * S[19];
    const float diff = f - y[n];
    float val = diff * diff;

    // Wave (=block, 64 threads) reduction, one atomic per block.
    #pragma unroll
    for (int off = 32; off > 0; off >>= 1)
        val += __shfl_down(val, off);
    if (threadIdx.x == 0)
        atomicAdd(out, val);
}

extern "C" void kernel_launch(void* const* d_in, const int* in_sizes, int n_in,
                              void* d_out, int out_size, void* d_ws, size_t ws_size,
                              hipStream_t stream) {
    const float* x      = (const float*)d_in[0];
    const float* y      = (const float*)d_in[1];
    const float* init_L = (const float*)d_in[2];
    const float* init_b = (const float*)d_in[3];
    const float* init_S = (const float*)d_in[4];
    const float* alpha  = (const float*)d_in[5];
    const float* beta   = (const float*)d_in[6];
    const float* gamma  = (const float*)d_in[7];
    float* out = (float*)d_out;

    const int N = in_sizes[1];          // number of windows (32768)

    hipMemsetAsync(d_out, 0, sizeof(float), stream);   // d_out is poisoned 0xAA
    holtwinter_kernel<<<N / 64, 64, 0, stream>>>(
        x, y, init_L, init_b, init_S, alpha, beta, gamma, out);
}